// Round 1
// baseline (921.484 us; speedup 1.0000x reference)
//
#include <hip/hip_runtime.h>

#define DIN 128
#define HID 128
#define BB  32
#define NN  2048
#define LOG2E 1.44269504088896340736f

typedef float  f32x4   __attribute__((ext_vector_type(4)));
typedef __bf16 bf16x4v __attribute__((ext_vector_type(4)));
typedef __bf16 bf16x8  __attribute__((ext_vector_type(8)));

__device__ __forceinline__ float tanh_fast(float x) {
  // tanh(x) = 1 - 2/(e^{2x}+1); NaN-free for +-inf of exp
  float e = __expf(2.0f * x);
  return 1.0f - 2.0f / (e + 1.0f);
}

// ---------------------------------------------------------------------------
// Kernel 0: W[d][h] (fp32) -> wt[h][d] (bf16), for q,k,v. 3 blocks x 256.
// ---------------------------------------------------------------------------
__global__ __launch_bounds__(256) void wt_kernel(
    const float* __restrict__ Wq, const float* __restrict__ Wk,
    const float* __restrict__ Wv, __bf16* __restrict__ wt) {
  const float* W = (blockIdx.x == 0) ? Wq : (blockIdx.x == 1) ? Wk : Wv;
  __bf16* dst = wt + blockIdx.x * (DIN * HID);
  int t = threadIdx.x;
#pragma unroll
  for (int c = 0; c < 16; ++c) {
    int o = c * 1024 + t * 4;
    int d = o >> 7, h = o & 127;
    f32x4 v = *(const f32x4*)(W + d * HID + h);
    dst[(h + 0) * DIN + d] = (__bf16)v.x;
    dst[(h + 1) * DIN + d] = (__bf16)v.y;
    dst[(h + 2) * DIN + d] = (__bf16)v.z;
    dst[(h + 3) * DIN + d] = (__bf16)v.w;
  }
}

// ---------------------------------------------------------------------------
// Kernel A: q = tanh(xWq+bq)*LOG2E, k = tanh(xWk+bk) row-major bf16 [B*N][H];
//           vt = tanh(xWv+bv)^T per batch, bf16 [B][H][N].
//           PLUS: mask[64 rows][2048] fp32 -> bitmask u32 [row][64].
// grid = B*N/64 blocks of 256 threads (4 waves; wave w owns rows 16w..16w+15).
// The mask compress turns this kernel into the 537 MB streaming pass; the
// MFMA/tanh work hides underneath the HBM stream (4 blocks/CU resident).
// ---------------------------------------------------------------------------
__global__ __launch_bounds__(256) void proj_kernel(
    const float* __restrict__ x, const __bf16* __restrict__ wt,
    const float* __restrict__ bq, const float* __restrict__ bk,
    const float* __restrict__ bv, const float* __restrict__ mask,
    __bf16* __restrict__ qbf, __bf16* __restrict__ kbf,
    __bf16* __restrict__ vtbf, unsigned* __restrict__ mbits) {
  int tid = threadIdx.x;
  int lane = tid & 63, w = tid >> 6;
  int l15 = lane & 15, quad = lane >> 4;
  long i0 = (long)blockIdx.x * 64;

  // x fragments: bx[nt][ks]: lane holds x[i0+nt*16+l15][ks*32+quad*8 .. +7]
  bf16x8 bx[4][4];
#pragma unroll
  for (int nt = 0; nt < 4; ++nt) {
    const float* xp = x + (i0 + nt * 16 + l15) * DIN;
#pragma unroll
    for (int ks = 0; ks < 4; ++ks) {
      int d0 = ks * 32 + quad * 8;
      f32x4 a = *(const f32x4*)(xp + d0);
      f32x4 b = *(const f32x4*)(xp + d0 + 4);
      bf16x8 f;
      f[0] = (__bf16)a.x; f[1] = (__bf16)a.y; f[2] = (__bf16)a.z; f[3] = (__bf16)a.w;
      f[4] = (__bf16)b.x; f[5] = (__bf16)b.y; f[6] = (__bf16)b.z; f[7] = (__bf16)b.w;
      bx[nt][ks] = f;
    }
  }

  // q and k: D[i][h] = sum_d x[i][d] * W[d][h]; A = x frag, B = wt[h][d]
#pragma unroll
  for (int p = 0; p < 2; ++p) {
    const __bf16* wtp = wt + p * DIN * HID;       // 0=q, 1=k
    const float* bias = (p == 0) ? bq : bk;
    __bf16* outp = (p == 0) ? qbf : kbf;
#pragma unroll
    for (int nt = 0; nt < 8; ++nt) {
      int h0 = nt * 16 + l15;
      f32x4 acc = {0.f, 0.f, 0.f, 0.f};
#pragma unroll
      for (int ks = 0; ks < 4; ++ks) {
        bf16x8 wf = *(const bf16x8*)(wtp + (long)h0 * DIN + ks * 32 + quad * 8);
        acc = __builtin_amdgcn_mfma_f32_16x16x32_bf16(bx[w][ks], wf, acc, 0, 0, 0);
      }
      float bcol = bias[h0];
      long rowb = i0 + w * 16 + quad * 4;
#pragma unroll
      for (int r = 0; r < 4; ++r) {
        float val = tanh_fast(acc[r] + bcol);
        if (p == 0) val *= LOG2E;   // fold log2(e) into q for exp2 softmax
        outp[(rowb + r) * HID + h0] = (__bf16)val;
      }
    }
  }

  // vt: D[h][n] = sum_d W[d][h] * x[n][d]; A = wt frag, B = x frag
  {
    const __bf16* wtp = wt + 2 * DIN * HID;
    long bb = i0 >> 11;            // batch index
    int nloc = (int)(i0 & 2047);   // row within batch
    long vbase = bb * (long)HID * NN;
#pragma unroll
    for (int s = 0; s < 2; ++s) {
      int hb = w * 32 + s * 16;
      bf16x8 af[4];
#pragma unroll
      for (int ks = 0; ks < 4; ++ks)
        af[ks] = *(const bf16x8*)(wtp + (long)(hb + l15) * DIN + ks * 32 + quad * 8);
      float bvr[4];
#pragma unroll
      for (int r = 0; r < 4; ++r) bvr[r] = bv[hb + quad * 4 + r];
#pragma unroll
      for (int nt = 0; nt < 4; ++nt) {
        f32x4 acc = {0.f, 0.f, 0.f, 0.f};
#pragma unroll
        for (int ks = 0; ks < 4; ++ks)
          acc = __builtin_amdgcn_mfma_f32_16x16x32_bf16(af[ks], bx[nt][ks], acc, 0, 0, 0);
        int hrow = hb + quad * 4;
        int ncol = nloc + nt * 16 + l15;
#pragma unroll
        for (int r = 0; r < 4; ++r) {
          float val = tanh_fast(acc[r] + bvr[r]);
          vtbf[vbase + (long)(hrow + r) * NN + ncol] = (__bf16)val;
        }
      }
    }
  }

  // ---- mask fp32 -> bitmask. Rows i0..i0+63 (global over B*N), cols 0..2047.
  // 16 iters x 256 threads, each thread builds 1 u32 from 128 B contiguous.
  // bit p of mbits[row][j] <-> mask[row][j*32 + p] != 0
  {
    for (int it = 0; it < 16; ++it) {
      int gid = it * 256 + tid;
      int r = gid >> 6, j = gid & 63;
      const float* p = mask + (i0 + r) * NN + j * 32;
      unsigned bits = 0;
#pragma unroll
      for (int c = 0; c < 8; ++c) {
        f32x4 v = *(const f32x4*)(p + c * 4);
        bits |= (v.x != 0.f ? 1u : 0u) << (c * 4 + 0);
        bits |= (v.y != 0.f ? 1u : 0u) << (c * 4 + 1);
        bits |= (v.z != 0.f ? 1u : 0u) << (c * 4 + 2);
        bits |= (v.w != 0.f ? 1u : 0u) << (c * 4 + 3);
      }
      mbits[(i0 + r) * 64 + j] = bits;
    }
  }
}

// ---------------------------------------------------------------------------
// Kernel B: flash attention, software-pipelined.
// grid = 512 blocks x 512 threads (8 waves). Block owns 128 q-rows.
// Wave w owns q rows i0+16w..+15 (i = lane&15 in the transposed-S layout).
// K-loop: 32 tiles of 64 keys; K/V/mask-bits for tile j+1 register-prefetched
// during compute of tile j, staged to (single-buffered) LDS after barrier.
// Mask arrives pre-compressed: one u64 per (row, tile) instead of 64 B fp32.
// ---------------------------------------------------------------------------
#define KSTR 136   // Ks row stride: 272 B, 16B-aligned
#define VSTR 72    // Vts row stride: 144 B, 16B-aligned
#define PSTR 72    // P row stride: 144 B, 16B-aligned

__global__ __launch_bounds__(512, 4) void attn_kernel(
    const __bf16* __restrict__ qbf, const __bf16* __restrict__ kbf,
    const __bf16* __restrict__ vtbf, const unsigned* __restrict__ mbits,
    float* __restrict__ out) {
  __shared__ __bf16 Ks[64 * KSTR];       // 17408 B
  __shared__ __bf16 Vts[128 * VSTR];     // 18432 B
  __shared__ __bf16 Pl[8 * 16 * PSTR];   // 18432 B  (total 54272 B)

  const int tid = threadIdx.x;
  const int lane = tid & 63, w = tid >> 6;
  const int l15 = lane & 15, quad = lane >> 4;
  // XCD swizzle: 64 consecutive virtual blocks (= 4 whole batches) per XCD
  const int bid = blockIdx.x;
  const int vb = (bid >> 3) | ((bid & 7) << 6);
  const int b = vb >> 4;
  const int i0 = (vb & 15) * 128;
  const long kvbase = (long)b * NN * HID;

  // Q fragment (B operand of S^T): lane l15 = q-row, quad*8+e = k-dim
  bf16x8 qf[4];
  {
    const __bf16* qp = qbf + kvbase + (long)(i0 + w * 16 + l15) * HID + quad * 8;
#pragma unroll
    for (int ks = 0; ks < 4; ++ks) qf[ks] = *(const bf16x8*)(qp + ks * 32);
  }

  // staging geometry (512 threads, 2 passes per tile for each of K and Vt)
  const int krow = tid >> 4, kcol = (tid & 15) * 8;
  const int vrow = tid >> 3, vcol = (tid & 7) * 8;
  const __bf16* kg = kbf + kvbase + (long)krow * HID + kcol;
  const __bf16* vg = vtbf + (long)b * HID * NN + (long)vrow * NN + vcol;
  __bf16* ksd0 = Ks + krow * KSTR + kcol;
  __bf16* ksd1 = Ks + (krow + 32) * KSTR + kcol;
  __bf16* vsd0 = Vts + vrow * VSTR + vcol;
  __bf16* vsd1 = Vts + (vrow + 64) * VSTR + vcol;
  // mask bits: lane's q-row, one u64 (= 64 key-bits) per tile
  const unsigned* mrp = mbits + ((long)b * NN + (i0 + w * 16 + l15)) * 64;
  __bf16* Pw = Pl + w * 16 * PSTR;

  f32x4 O[8];
#pragma unroll
  for (int i = 0; i < 8; ++i) O[i] = (f32x4){0.f, 0.f, 0.f, 0.f};
  float mrow = -1e30f, lrow = 0.0f;   // per q-row i = l15 (replicated over quads)

  // ---- prologue: load + stage tile 0
  bf16x8 kr0 = *(const bf16x8*)(kg);
  bf16x8 kr1 = *(const bf16x8*)(kg + 32 * HID);
  bf16x8 vr0 = *(const bf16x8*)(vg);
  bf16x8 vr1 = *(const bf16x8*)(vg + (long)64 * NN);
  unsigned long long mw = *(const unsigned long long*)(mrp);
  *(bf16x8*)ksd0 = kr0; *(bf16x8*)ksd1 = kr1;
  *(bf16x8*)vsd0 = vr0; *(bf16x8*)vsd1 = vr1;
  __syncthreads();

  for (int jt = 0; jt < 32; ++jt) {
    const int jn = (jt < 31) ? jt + 1 : 31;   // redundant reload on last iter
    // ---- issue prefetch for tile jn (in flight across the whole compute phase)
    unsigned long long mwn;
    {
      const __bf16* kgn = kg + (long)jn * 64 * HID;
      kr0 = *(const bf16x8*)(kgn);
      kr1 = *(const bf16x8*)(kgn + 32 * HID);
      const __bf16* vgn = vg + jn * 64;
      vr0 = *(const bf16x8*)(vgn);
      vr1 = *(const bf16x8*)(vgn + (long)64 * NN);
      mwn = *(const unsigned long long*)(mrp + jn * 2);
    }

    // ---- S^T = K Q^T : rows = keys (quad*4+r within subtile t), cols = q (l15)
    f32x4 pt[4];
#pragma unroll
    for (int t = 0; t < 4; ++t) {
      f32x4 acc = {0.f, 0.f, 0.f, 0.f};
      const __bf16* kp = Ks + (t * 16 + l15) * KSTR + quad * 8;
#pragma unroll
      for (int ks = 0; ks < 4; ++ks) {
        bf16x8 kf = *(const bf16x8*)(kp + ks * 32);
        acc = __builtin_amdgcn_mfma_f32_16x16x32_bf16(kf, qf[ks], acc, 0, 0, 0);
      }
      pt[t] = acc;
    }

    // ---- per-lane 16 mask bits for keys t*16+quad*4+r, from this tile's u64
    unsigned mb16 = 0;
#pragma unroll
    for (int t = 0; t < 4; ++t)
      mb16 |= ((unsigned)(mw >> (t * 16 + (quad << 2))) & 0xFu) << (t * 4);

    // ---- masked online softmax (log2 domain; q pre-scaled by log2 e)
    float tmx = -1e30f;
#pragma unroll
    for (int t = 0; t < 4; ++t)
#pragma unroll
      for (int r = 0; r < 4; ++r) {
        float s = ((mb16 >> (t * 4 + r)) & 1u) ? pt[t][r] : -1e30f;
        pt[t][r] = s;
        tmx = fmaxf(tmx, s);
      }
    tmx = fmaxf(tmx, __shfl_xor(tmx, 16));
    tmx = fmaxf(tmx, __shfl_xor(tmx, 32));
    const bool grow = !__all(tmx <= mrow);   // any row max increased?
    const float mnew = fmaxf(mrow, tmx);
    const float alpha = exp2f(mrow - mnew);  // == 1.0 exactly when !grow
    float rs = 0.0f;
#pragma unroll
    for (int t = 0; t < 4; ++t)
#pragma unroll
      for (int r = 0; r < 4; ++r) {
        float p = exp2f(pt[t][r] - mnew);
        pt[t][r] = p;
        rs += p;
      }
    rs += __shfl_xor(rs, 16);
    rs += __shfl_xor(rs, 32);
    lrow = lrow * alpha + rs;
    mrow = mnew;

    // ---- rescale O (O rows are i = quad*4+r; alpha lives at lane l15 = i)
    if (grow) {
      float ar[4];
#pragma unroll
      for (int r = 0; r < 4; ++r) ar[r] = __shfl(alpha, (quad << 2) + r);
#pragma unroll
      for (int nt = 0; nt < 8; ++nt)
#pragma unroll
        for (int r = 0; r < 4; ++r) O[nt][r] *= ar[r];
    }

    // ---- P: S^T layout -> LDS [i][j] -> A-layout (wave-private, b64 writes)
#pragma unroll
    for (int t = 0; t < 4; ++t) {
      bf16x4v pb;
#pragma unroll
      for (int r = 0; r < 4; ++r) pb[r] = (__bf16)pt[t][r];
      *(bf16x4v*)(Pw + l15 * PSTR + t * 16 + quad * 4) = pb;
    }
    const bf16x8 pf0 = *(const bf16x8*)(Pw + l15 * PSTR + quad * 8);
    const bf16x8 pf1 = *(const bf16x8*)(Pw + l15 * PSTR + 32 + quad * 8);

    // ---- O += P V
#pragma unroll
    for (int nt = 0; nt < 8; ++nt) {
      const __bf16* vp = Vts + (nt * 16 + l15) * VSTR + quad * 8;
      bf16x8 vf0 = *(const bf16x8*)(vp);
      bf16x8 vf1 = *(const bf16x8*)(vp + 32);
      O[nt] = __builtin_amdgcn_mfma_f32_16x16x32_bf16(pf0, vf0, O[nt], 0, 0, 0);
      O[nt] = __builtin_amdgcn_mfma_f32_16x16x32_bf16(pf1, vf1, O[nt], 0, 0, 0);
    }

    __syncthreads();   // all waves done reading tile jt from LDS
    // ---- stage prefetched tile jn into LDS; swap in its mask word
    *(bf16x8*)ksd0 = kr0; *(bf16x8*)ksd1 = kr1;
    *(bf16x8*)vsd0 = vr0; *(bf16x8*)vsd1 = vr1;
    mw = mwn;
    __syncthreads();   // tile jn visible to all waves
  }

  // ---- epilogue: out[i][h] = O / l
  const float inv = 1.0f / lrow;
  float il[4];
#pragma unroll
  for (int r = 0; r < 4; ++r) il[r] = __shfl(inv, (quad << 2) + r);
  const long rowb = (long)b * NN + i0 + w * 16 + quad * 4;
#pragma unroll
  for (int r = 0; r < 4; ++r) {
    float* op = out + (rowb + r) * HID;
#pragma unroll
    for (int nt = 0; nt < 8; ++nt) op[nt * 16 + l15] = O[nt][r] * il[r];
  }
}

// ---------------------------------------------------------------------------
extern "C" void kernel_launch(void* const* d_in, const int* in_sizes, int n_in,
                              void* d_out, int out_size, void* d_ws, size_t ws_size,
                              hipStream_t stream) {
  const float* x    = (const float*)d_in[0];
  const float* mask = (const float*)d_in[1];
  const float* Wv   = (const float*)d_in[2];
  const float* bv   = (const float*)d_in[3];
  const float* Wk   = (const float*)d_in[4];
  const float* bk   = (const float*)d_in[5];
  const float* Wq   = (const float*)d_in[6];
  const float* bq   = (const float*)d_in[7];
  float* out = (float*)d_out;

  __bf16* ws = (__bf16*)d_ws;
  __bf16* wt   = ws;                      // 3 * 128*128
  __bf16* qbf  = ws + 3 * DIN * HID;      // B*N*H
  __bf16* kbf  = qbf + (long)BB * NN * HID;
  __bf16* vtbf = kbf + (long)BB * NN * HID;
  unsigned* mbits = (unsigned*)(vtbf + (long)BB * NN * HID);  // B*N*64 u32

  wt_kernel<<<3, 256, 0, stream>>>(Wq, Wk, Wv, wt);
  proj_kernel<<<BB * NN / 64, 256, 0, stream>>>(x, wt, bq, bk, bv, mask,
                                                qbf, kbf, vtbf, mbits);
  attn_kernel<<<512, 512, 0, stream>>>(qbf, kbf, vtbf, mbits, out);
}

// Round 2
// 893.304 us; speedup vs baseline: 1.0315x; 1.0315x over previous
//
#include <hip/hip_runtime.h>

#define DIN 128
#define HID 128
#define BB  32
#define NN  2048
#define LOG2E 1.44269504088896340736f

typedef float  f32x4   __attribute__((ext_vector_type(4)));
typedef __bf16 bf16x4v __attribute__((ext_vector_type(4)));
typedef __bf16 bf16x8  __attribute__((ext_vector_type(8)));

__device__ __forceinline__ float tanh_fast(float x) {
  // tanh(x) = 1 - 2/(e^{2x}+1); NaN-free for +-inf of exp
  float e = __expf(2.0f * x);
  return 1.0f - 2.0f / (e + 1.0f);
}

// ---------------------------------------------------------------------------
// Kernel 0: W[d][h] (fp32) -> wt[h][d] (bf16), for q,k,v. 3 blocks x 256.
// ---------------------------------------------------------------------------
__global__ __launch_bounds__(256) void wt_kernel(
    const float* __restrict__ Wq, const float* __restrict__ Wk,
    const float* __restrict__ Wv, __bf16* __restrict__ wt) {
  const float* W = (blockIdx.x == 0) ? Wq : (blockIdx.x == 1) ? Wk : Wv;
  __bf16* dst = wt + blockIdx.x * (DIN * HID);
  int t = threadIdx.x;
#pragma unroll
  for (int c = 0; c < 16; ++c) {
    int o = c * 1024 + t * 4;
    int d = o >> 7, h = o & 127;
    f32x4 v = *(const f32x4*)(W + d * HID + h);
    dst[(h + 0) * DIN + d] = (__bf16)v.x;
    dst[(h + 1) * DIN + d] = (__bf16)v.y;
    dst[(h + 2) * DIN + d] = (__bf16)v.z;
    dst[(h + 3) * DIN + d] = (__bf16)v.w;
  }
}

// ---------------------------------------------------------------------------
// Kernel A: q = tanh(xWq+bq)*LOG2E, k = tanh(xWk+bk) row-major bf16 [B*N][H];
//           vt = tanh(xWv+bv)^T per batch, bf16 [B][H][N].
// grid = B*N/64 blocks of 256 threads (4 waves; wave w owns rows 16w..16w+15).
// ---------------------------------------------------------------------------
__global__ __launch_bounds__(256) void proj_kernel(
    const float* __restrict__ x, const __bf16* __restrict__ wt,
    const float* __restrict__ bq, const float* __restrict__ bk,
    const float* __restrict__ bv, __bf16* __restrict__ qbf,
    __bf16* __restrict__ kbf, __bf16* __restrict__ vtbf) {
  int tid = threadIdx.x;
  int lane = tid & 63, w = tid >> 6;
  int l15 = lane & 15, quad = lane >> 4;
  long i0 = (long)blockIdx.x * 64;

  // x fragments: bx[nt][ks]: lane holds x[i0+nt*16+l15][ks*32+quad*8 .. +7]
  bf16x8 bx[4][4];
#pragma unroll
  for (int nt = 0; nt < 4; ++nt) {
    const float* xp = x + (i0 + nt * 16 + l15) * DIN;
#pragma unroll
    for (int ks = 0; ks < 4; ++ks) {
      int d0 = ks * 32 + quad * 8;
      f32x4 a = *(const f32x4*)(xp + d0);
      f32x4 b = *(const f32x4*)(xp + d0 + 4);
      bf16x8 f;
      f[0] = (__bf16)a.x; f[1] = (__bf16)a.y; f[2] = (__bf16)a.z; f[3] = (__bf16)a.w;
      f[4] = (__bf16)b.x; f[5] = (__bf16)b.y; f[6] = (__bf16)b.z; f[7] = (__bf16)b.w;
      bx[nt][ks] = f;
    }
  }

  // q and k: D[i][h] = sum_d x[i][d] * W[d][h]; A = x frag, B = wt[h][d]
#pragma unroll
  for (int p = 0; p < 2; ++p) {
    const __bf16* wtp = wt + p * DIN * HID;       // 0=q, 1=k
    const float* bias = (p == 0) ? bq : bk;
    __bf16* outp = (p == 0) ? qbf : kbf;
#pragma unroll
    for (int nt = 0; nt < 8; ++nt) {
      int h0 = nt * 16 + l15;
      f32x4 acc = {0.f, 0.f, 0.f, 0.f};
#pragma unroll
      for (int ks = 0; ks < 4; ++ks) {
        bf16x8 wf = *(const bf16x8*)(wtp + (long)h0 * DIN + ks * 32 + quad * 8);
        acc = __builtin_amdgcn_mfma_f32_16x16x32_bf16(bx[w][ks], wf, acc, 0, 0, 0);
      }
      float bcol = bias[h0];
      long rowb = i0 + w * 16 + quad * 4;
#pragma unroll
      for (int r = 0; r < 4; ++r) {
        float val = tanh_fast(acc[r] + bcol);
        if (p == 0) val *= LOG2E;   // fold log2(e) into q for exp2 softmax
        outp[(rowb + r) * HID + h0] = (__bf16)val;
      }
    }
  }

  // vt: D[h][n] = sum_d W[d][h] * x[n][d]; A = wt frag, B = x frag
  {
    const __bf16* wtp = wt + 2 * DIN * HID;
    long bb = i0 >> 11;            // batch index
    int nloc = (int)(i0 & 2047);   // row within batch
    long vbase = bb * (long)HID * NN;
#pragma unroll
    for (int s = 0; s < 2; ++s) {
      int hb = w * 32 + s * 16;
      bf16x8 af[4];
#pragma unroll
      for (int ks = 0; ks < 4; ++ks)
        af[ks] = *(const bf16x8*)(wtp + (long)(hb + l15) * DIN + ks * 32 + quad * 8);
      float bvr[4];
#pragma unroll
      for (int r = 0; r < 4; ++r) bvr[r] = bv[hb + quad * 4 + r];
#pragma unroll
      for (int nt = 0; nt < 4; ++nt) {
        f32x4 acc = {0.f, 0.f, 0.f, 0.f};
#pragma unroll
        for (int ks = 0; ks < 4; ++ks)
          acc = __builtin_amdgcn_mfma_f32_16x16x32_bf16(af[ks], bx[nt][ks], acc, 0, 0, 0);
        int hrow = hb + quad * 4;
        int ncol = nloc + nt * 16 + l15;
#pragma unroll
        for (int r = 0; r < 4; ++r) {
          float val = tanh_fast(acc[r] + bvr[r]);
          vtbf[vbase + (long)(hrow + r) * NN + ncol] = (__bf16)val;
        }
      }
    }
  }
}

// ---------------------------------------------------------------------------
// Kernel B: flash attention, double-buffered LDS, ONE barrier per tile.
// grid = 512 blocks x 512 threads (8 waves). Block owns 128 q-rows.
// K stored [64][128] bf16, V^T stored [128][64] bf16, both XOR-swizzled
// (elem ^= (row&7)<<3) for bank spread, x2 buffers = 64 KiB total LDS.
// P (per-wave 16x64) lives inside the wave's OWN 8-row slice of the
// INACTIVE K buffer (dead K data); the same wave later overwrites that
// slice with its K-staging rows, so no cross-wave race with one barrier.
// ---------------------------------------------------------------------------
__global__ __launch_bounds__(512, 4) void attn_kernel(
    const __bf16* __restrict__ qbf, const __bf16* __restrict__ kbf,
    const __bf16* __restrict__ vtbf, const float* __restrict__ mask,
    float* __restrict__ out) {
  __shared__ __bf16 Ks[2][64 * 128];    // 2 x 16 KiB
  __shared__ __bf16 Vts[2][128 * 64];   // 2 x 16 KiB   (total 64 KiB)

  const int tid = threadIdx.x;
  const int lane = tid & 63, w = tid >> 6;
  const int l15 = lane & 15, quad = lane >> 4;
  const int swz = (l15 & 7) << 3;       // element-XOR for rows with row&7==l15&7
  // XCD swizzle: 64 consecutive virtual blocks (= 4 whole batches) per XCD
  const int bid = blockIdx.x;
  const int vb = (bid >> 3) | ((bid & 7) << 6);
  const int b = vb >> 4;
  const int i0 = (vb & 15) * 128;
  const long kvbase = (long)b * NN * HID;

  // Q fragment (B operand of S^T): lane l15 = q-row, quad*8+e = k-dim
  bf16x8 qf[4];
  {
    const __bf16* qp = qbf + kvbase + (long)(i0 + w * 16 + l15) * HID + quad * 8;
#pragma unroll
    for (int ks = 0; ks < 4; ++ks) qf[ks] = *(const bf16x8*)(qp + ks * 32);
  }

  // staging geometry: wave w stages K rows [8w,8w+8) and V rows [16w,16w+16)
  const int krl = (w << 3) + (lane >> 3);       // K row in tile [0,64)
  const int kcl = (lane & 7) * 8;               // K col elem; second at +64
  const int vrl = (w << 4) + (lane >> 2);       // V row [0,128)
  const int vcl = (lane & 3) * 8;               // V col elem; second at +32
  const __bf16* kg = kbf + kvbase + (long)krl * HID + kcl;
  const __bf16* vg = vtbf + (long)b * HID * NN + (long)vrl * NN + vcl;
  const int ksw0 = krl * 128 + (kcl ^ ((krl & 7) << 3));
  const int ksw1 = krl * 128 + ((kcl + 64) ^ ((krl & 7) << 3));
  const int vsw0 = vrl * 64 + (vcl ^ ((vrl & 7) << 3));
  const int vsw1 = vrl * 64 + ((vcl + 32) ^ ((vrl & 7) << 3));
  // mask: lane reads row i = i0+w*16+l15, 4 consecutive cols at quad*4
  const float* mp = mask + ((long)b * NN + (i0 + w * 16 + l15)) * NN + quad * 4;

  f32x4 O[8];
#pragma unroll
  for (int i = 0; i < 8; ++i) O[i] = (f32x4){0.f, 0.f, 0.f, 0.f};
  float mrow = -1e30f, lrow = 0.0f;   // per q-row i = l15 (replicated over quads)

  // ---- prologue: load + stage tile 0 into buffer 0
  bf16x8 kr0 = *(const bf16x8*)(kg);
  bf16x8 kr1 = *(const bf16x8*)(kg + 64);
  bf16x8 vr0 = *(const bf16x8*)(vg);
  bf16x8 vr1 = *(const bf16x8*)(vg + 32);
  f32x4 mr[4];
#pragma unroll
  for (int t = 0; t < 4; ++t) mr[t] = *(const f32x4*)(mp + t * 16);
  *(bf16x8*)&Ks[0][ksw0] = kr0; *(bf16x8*)&Ks[0][ksw1] = kr1;
  *(bf16x8*)&Vts[0][vsw0] = vr0; *(bf16x8*)&Vts[0][vsw1] = vr1;
  unsigned mbits;
  {
    float mb = 0.f;
#pragma unroll
    for (int t = 0; t < 4; ++t)
#pragma unroll
      for (int r = 0; r < 4; ++r)
        mb = fmaf(mr[t][r], (float)(1u << (t * 4 + r)), mb);  // mask is exactly 0/1
    mbits = (unsigned)mb;
  }
  __syncthreads();

  int cur = 0;
  for (int jt = 0; jt < 32; ++jt) {
    const int jn = (jt < 31) ? jt + 1 : 31;   // redundant reload on last iter
    // ---- issue prefetch for tile jn (in flight across the whole compute phase)
    {
      const __bf16* kgn = kg + (long)jn * 64 * HID;
      kr0 = *(const bf16x8*)(kgn);
      kr1 = *(const bf16x8*)(kgn + 64);
      const __bf16* vgn = vg + jn * 64;
      vr0 = *(const bf16x8*)(vgn);
      vr1 = *(const bf16x8*)(vgn + 32);
#pragma unroll
      for (int t = 0; t < 4; ++t) mr[t] = *(const f32x4*)(mp + jn * 64 + t * 16);
    }

    // ---- S^T = K Q^T : rows = keys (quad*4+r within subtile t), cols = q (l15)
    f32x4 pt[4];
#pragma unroll
    for (int t = 0; t < 4; ++t) {
      f32x4 acc = {0.f, 0.f, 0.f, 0.f};
      const int krow = t * 16 + l15;          // krow&7 == l15&7
#pragma unroll
      for (int ks = 0; ks < 4; ++ks) {
        bf16x8 kf = *(const bf16x8*)&Ks[cur][krow * 128 + ((quad * 8 + ks * 32) ^ swz)];
        acc = __builtin_amdgcn_mfma_f32_16x16x32_bf16(kf, qf[ks], acc, 0, 0, 0);
      }
      pt[t] = acc;
    }

    // ---- masked online softmax (log2 domain; q pre-scaled by log2 e)
    float tmx = -1e30f;
#pragma unroll
    for (int t = 0; t < 4; ++t)
#pragma unroll
      for (int r = 0; r < 4; ++r) {
        float s = ((mbits >> (t * 4 + r)) & 1u) ? pt[t][r] : -1e30f;
        pt[t][r] = s;
        tmx = fmaxf(tmx, s);
      }
    tmx = fmaxf(tmx, __shfl_xor(tmx, 16));
    tmx = fmaxf(tmx, __shfl_xor(tmx, 32));
    const bool grow = !__all(tmx <= mrow);   // any row max increased?
    const float mnew = fmaxf(mrow, tmx);
    const float alpha = exp2f(mrow - mnew);  // == 1.0 exactly when !grow
    float rs = 0.0f;
#pragma unroll
    for (int t = 0; t < 4; ++t)
#pragma unroll
      for (int r = 0; r < 4; ++r) {
        float p = exp2f(pt[t][r] - mnew);
        pt[t][r] = p;
        rs += p;
      }
    rs += __shfl_xor(rs, 16);
    rs += __shfl_xor(rs, 32);
    lrow = lrow * alpha + rs;
    mrow = mnew;

    // ---- rescale O (O rows are i = quad*4+r; alpha lives at lane l15 = i)
    if (grow) {
      float ar[4];
#pragma unroll
      for (int r = 0; r < 4; ++r) ar[r] = __shfl(alpha, (quad << 2) + r);
#pragma unroll
      for (int nt = 0; nt < 8; ++nt)
#pragma unroll
        for (int r = 0; r < 4; ++r) O[nt][r] *= ar[r];
    }

    // ---- P: S^T layout -> wave slice of INACTIVE K buffer -> A-layout
    __bf16* Pw = &Ks[cur ^ 1][w * 1024];     // rows [8w,8w+8) = this wave's slice
#pragma unroll
    for (int t = 0; t < 4; ++t) {
      bf16x4v pb;
#pragma unroll
      for (int r = 0; r < 4; ++r) pb[r] = (__bf16)pt[t][r];
      *(bf16x4v*)&Pw[l15 * 64 + ((t * 16 + quad * 4) ^ swz)] = pb;
    }
    const bf16x8 pf0 = *(const bf16x8*)&Pw[l15 * 64 + ((quad * 8) ^ swz)];
    const bf16x8 pf1 = *(const bf16x8*)&Pw[l15 * 64 + ((quad * 8 + 32) ^ swz)];

    // ---- O += P V
#pragma unroll
    for (int nt = 0; nt < 8; ++nt) {
      const int vrow = nt * 16 + l15;         // vrow&7 == l15&7
      bf16x8 vf0 = *(const bf16x8*)&Vts[cur][vrow * 64 + ((quad * 8) ^ swz)];
      bf16x8 vf1 = *(const bf16x8*)&Vts[cur][vrow * 64 + ((quad * 8 + 32) ^ swz)];
      O[nt] = __builtin_amdgcn_mfma_f32_16x16x32_bf16(pf0, vf0, O[nt], 0, 0, 0);
      O[nt] = __builtin_amdgcn_mfma_f32_16x16x32_bf16(pf1, vf1, O[nt], 0, 0, 0);
    }

    // ---- stage prefetched tile jn into the inactive buffers (overwrites this
    // wave's own P slice only; other waves' slices untouched -> race-free)
    *(bf16x8*)&Ks[cur ^ 1][ksw0] = kr0; *(bf16x8*)&Ks[cur ^ 1][ksw1] = kr1;
    *(bf16x8*)&Vts[cur ^ 1][vsw0] = vr0; *(bf16x8*)&Vts[cur ^ 1][vsw1] = vr1;
    {
      float mb = 0.f;
#pragma unroll
      for (int t = 0; t < 4; ++t)
#pragma unroll
        for (int r = 0; r < 4; ++r)
          mb = fmaf(mr[t][r], (float)(1u << (t * 4 + r)), mb);
      mbits = (unsigned)mb;
    }
    __syncthreads();   // tile jn staged & visible; everyone done with tile jt
    cur ^= 1;
  }

  // ---- epilogue: out[i][h] = O / l
  const float inv = 1.0f / lrow;
  float il[4];
#pragma unroll
  for (int r = 0; r < 4; ++r) il[r] = __shfl(inv, (quad << 2) + r);
  const long rowb = (long)b * NN + i0 + w * 16 + quad * 4;
#pragma unroll
  for (int r = 0; r < 4; ++r) {
    float* op = out + (rowb + r) * HID;
#pragma unroll
    for (int nt = 0; nt < 8; ++nt) op[nt * 16 + l15] = O[nt][r] * il[r];
  }
}

// ---------------------------------------------------------------------------
extern "C" void kernel_launch(void* const* d_in, const int* in_sizes, int n_in,
                              void* d_out, int out_size, void* d_ws, size_t ws_size,
                              hipStream_t stream) {
  const float* x    = (const float*)d_in[0];
  const float* mask = (const float*)d_in[1];
  const float* Wv   = (const float*)d_in[2];
  const float* bv   = (const float*)d_in[3];
  const float* Wk   = (const float*)d_in[4];
  const float* bk   = (const float*)d_in[5];
  const float* Wq   = (const float*)d_in[6];
  const float* bq   = (const float*)d_in[7];
  float* out = (float*)d_out;

  __bf16* ws = (__bf16*)d_ws;
  __bf16* wt   = ws;                      // 3 * 128*128
  __bf16* qbf  = ws + 3 * DIN * HID;      // B*N*H
  __bf16* kbf  = qbf + (long)BB * NN * HID;
  __bf16* vtbf = kbf + (long)BB * NN * HID;

  wt_kernel<<<3, 256, 0, stream>>>(Wq, Wk, Wv, wt);
  proj_kernel<<<BB * NN / 64, 256, 0, stream>>>(x, wt, bq, bk, bv, qbf, kbf, vtbf);
  attn_kernel<<<512, 512, 0, stream>>>(qbf, kbf, vtbf, mask, out);
}

// Round 3
// 874.323 us; speedup vs baseline: 1.0539x; 1.0217x over previous
//
#include <hip/hip_runtime.h>

#define DIN 128
#define HID 128
#define BB  32
#define NN  2048
#define LOG2E 1.44269504088896340736f

typedef float  f32x4   __attribute__((ext_vector_type(4)));
typedef float  f32x16  __attribute__((ext_vector_type(16)));
typedef __bf16 bf16x4v __attribute__((ext_vector_type(4)));
typedef __bf16 bf16x8  __attribute__((ext_vector_type(8)));

__device__ __forceinline__ float tanh_fast(float x) {
  // tanh(x) = 1 - 2/(e^{2x}+1); NaN-free for +-inf of exp
  float e = __expf(2.0f * x);
  return 1.0f - 2.0f / (e + 1.0f);
}

__device__ __forceinline__ unsigned pack2bf(float x, float y) {
  union { unsigned u; __bf16 h[2]; } t;
  t.h[0] = (__bf16)x; t.h[1] = (__bf16)y;
  return t.u;   // compiler emits v_cvt_pk_bf16_f32
}

// ---------------------------------------------------------------------------
// Kernel 0: W[d][h] (fp32) -> wt[h][d] (bf16), for q,k,v. 3 blocks x 256.
// ---------------------------------------------------------------------------
__global__ __launch_bounds__(256) void wt_kernel(
    const float* __restrict__ Wq, const float* __restrict__ Wk,
    const float* __restrict__ Wv, __bf16* __restrict__ wt) {
  const float* W = (blockIdx.x == 0) ? Wq : (blockIdx.x == 1) ? Wk : Wv;
  __bf16* dst = wt + blockIdx.x * (DIN * HID);
  int t = threadIdx.x;
#pragma unroll
  for (int c = 0; c < 16; ++c) {
    int o = c * 1024 + t * 4;
    int d = o >> 7, h = o & 127;
    f32x4 v = *(const f32x4*)(W + d * HID + h);
    dst[(h + 0) * DIN + d] = (__bf16)v.x;
    dst[(h + 1) * DIN + d] = (__bf16)v.y;
    dst[(h + 2) * DIN + d] = (__bf16)v.z;
    dst[(h + 3) * DIN + d] = (__bf16)v.w;
  }
}

// ---------------------------------------------------------------------------
// Kernel A (unchanged, known-good): q = tanh(xWq+bq)*LOG2E, k = tanh(xWk+bk)
// row-major bf16 [B*N][H]; vt = tanh(xWv+bv)^T per batch, bf16 [B][H][N].
// ---------------------------------------------------------------------------
__global__ __launch_bounds__(256) void proj_kernel(
    const float* __restrict__ x, const __bf16* __restrict__ wt,
    const float* __restrict__ bq, const float* __restrict__ bk,
    const float* __restrict__ bv, __bf16* __restrict__ qbf,
    __bf16* __restrict__ kbf, __bf16* __restrict__ vtbf) {
  int tid = threadIdx.x;
  int lane = tid & 63, w = tid >> 6;
  int l15 = lane & 15, quad = lane >> 4;
  long i0 = (long)blockIdx.x * 64;

  bf16x8 bx[4][4];
#pragma unroll
  for (int nt = 0; nt < 4; ++nt) {
    const float* xp = x + (i0 + nt * 16 + l15) * DIN;
#pragma unroll
    for (int ks = 0; ks < 4; ++ks) {
      int d0 = ks * 32 + quad * 8;
      f32x4 a = *(const f32x4*)(xp + d0);
      f32x4 b = *(const f32x4*)(xp + d0 + 4);
      bf16x8 f;
      f[0] = (__bf16)a.x; f[1] = (__bf16)a.y; f[2] = (__bf16)a.z; f[3] = (__bf16)a.w;
      f[4] = (__bf16)b.x; f[5] = (__bf16)b.y; f[6] = (__bf16)b.z; f[7] = (__bf16)b.w;
      bx[nt][ks] = f;
    }
  }

#pragma unroll
  for (int p = 0; p < 2; ++p) {
    const __bf16* wtp = wt + p * DIN * HID;
    const float* bias = (p == 0) ? bq : bk;
    __bf16* outp = (p == 0) ? qbf : kbf;
#pragma unroll
    for (int nt = 0; nt < 8; ++nt) {
      int h0 = nt * 16 + l15;
      f32x4 acc = {0.f, 0.f, 0.f, 0.f};
#pragma unroll
      for (int ks = 0; ks < 4; ++ks) {
        bf16x8 wf = *(const bf16x8*)(wtp + (long)h0 * DIN + ks * 32 + quad * 8);
        acc = __builtin_amdgcn_mfma_f32_16x16x32_bf16(bx[w][ks], wf, acc, 0, 0, 0);
      }
      float bcol = bias[h0];
      long rowb = i0 + w * 16 + quad * 4;
#pragma unroll
      for (int r = 0; r < 4; ++r) {
        float val = tanh_fast(acc[r] + bcol);
        if (p == 0) val *= LOG2E;
        outp[(rowb + r) * HID + h0] = (__bf16)val;
      }
    }
  }

  {
    const __bf16* wtp = wt + 2 * DIN * HID;
    long bb = i0 >> 11;
    int nloc = (int)(i0 & 2047);
    long vbase = bb * (long)HID * NN;
#pragma unroll
    for (int s = 0; s < 2; ++s) {
      int hb = w * 32 + s * 16;
      bf16x8 af[4];
#pragma unroll
      for (int ks = 0; ks < 4; ++ks)
        af[ks] = *(const bf16x8*)(wtp + (long)(hb + l15) * DIN + ks * 32 + quad * 8);
      float bvr[4];
#pragma unroll
      for (int r = 0; r < 4; ++r) bvr[r] = bv[hb + quad * 4 + r];
#pragma unroll
      for (int nt = 0; nt < 4; ++nt) {
        f32x4 acc = {0.f, 0.f, 0.f, 0.f};
#pragma unroll
        for (int ks = 0; ks < 4; ++ks)
          acc = __builtin_amdgcn_mfma_f32_16x16x32_bf16(af[ks], bx[nt][ks], acc, 0, 0, 0);
        int hrow = hb + quad * 4;
        int ncol = nloc + nt * 16 + l15;
#pragma unroll
        for (int r = 0; r < 4; ++r) {
          float val = tanh_fast(acc[r] + bvr[r]);
          vtbf[vbase + (long)(hrow + r) * NN + ncol] = (__bf16)val;
        }
      }
    }
  }
}

// ---------------------------------------------------------------------------
// Kernel B: flash attention on 32x32x16 MFMA.
// grid = 512 blocks x 256 threads (4 waves; wave owns 32 q-rows).
// S^T = K·Q^T per 32x32 MFMA: C/D col = lane&31 = q, row = key
//   (m74/m101 layout) -> softmax is in-lane over 32 keys + shfl_xor(32);
//   P never touches LDS (cross-half exchange via shfl_xor(32)).
// O^T = V^T·P^T: A = V^T frags from LDS, B = P^T in regs.
// K [64][128] / V^T [128][64] double-buffered, XOR-swizzled; 1 barrier/tile.
// LDS reads per MFMA halve vs 16x16x32 (16B A-operand feeds 2x MACs).
// ---------------------------------------------------------------------------
__global__ __launch_bounds__(256, 2) void attn_kernel(
    const __bf16* __restrict__ qbf, const __bf16* __restrict__ kbf,
    const __bf16* __restrict__ vtbf, const float* __restrict__ mask,
    float* __restrict__ out) {
  __shared__ __bf16 Ks[2][64 * 128];    // 2 x 16 KiB
  __shared__ __bf16 Vts[2][128 * 64];   // 2 x 16 KiB   (total 64 KiB)

  const int tid = threadIdx.x;
  const int lane = tid & 63, w = tid >> 6;
  const int l31 = lane & 31, H = lane >> 5;
  const int swz = (l31 & 7) << 3;       // element-XOR for rows with row&7==l31&7
  // XCD swizzle: 64 consecutive virtual blocks (= 4 whole batches) per XCD
  const int bid = blockIdx.x;
  const int vb = (bid >> 3) | ((bid & 7) << 6);
  const int b = vb >> 4;
  const int i0 = (vb & 15) * 128;
  const long kvbase = (long)b * NN * HID;
  const int qrow = i0 + w * 32 + l31;   // this lane's q-row (local to batch)

  // Q fragments (B operand): col = q = l31, k-dim d = kd*16 + H*8 + e
  bf16x8 qf[8];
  {
    const __bf16* qp = qbf + kvbase + (long)qrow * HID + H * 8;
#pragma unroll
    for (int kd = 0; kd < 8; ++kd) qf[kd] = *(const bf16x8*)(qp + kd * 16);
  }

  // --- staging geometry ---
  // K tile is 16 KiB CONTIGUOUS in global: thread t copies 4x16B linearly.
  // dest row = u*16 + (t>>4), col = (t&15)*8  (row&7 == (t>>4)&7 for all u)
  const __bf16* kg = kbf + kvbase + (long)tid * 8;
  const int ksw = (tid >> 4) * 128 + (((tid & 15) * 8) ^ (((tid >> 4) & 7) << 3));
  // V^T: row = t>>1 (0..127), cols (t&1)*32 + u*8
  const int vrow = tid >> 1, vcolb = (tid & 1) * 32;
  const __bf16* vg = vtbf + (long)b * HID * NN + (long)vrow * NN + vcolb;
  int vsw[4];
#pragma unroll
  for (int u = 0; u < 4; ++u)
    vsw[u] = vrow * 64 + ((vcolb + u * 8) ^ ((vrow & 7) << 3));
  // mask: lane's q-row; per tile needs keys {8g + 4H + e}
  const float* mp = mask + ((long)b * NN + qrow) * NN + H * 4;

  f32x16 O[4];
#pragma unroll
  for (int ht = 0; ht < 4; ++ht)
#pragma unroll
    for (int r = 0; r < 16; ++r) O[ht][r] = 0.f;
  float mrow = -1e30f, lrow = 0.0f;     // per q-row, replicated across halves

  // ---- prologue: load + stage tile 0 into buffer 0
  bf16x8 kr[4], vr[4];
  f32x4 mr[8];
#pragma unroll
  for (int u = 0; u < 4; ++u) kr[u] = *(const bf16x8*)(kg + u * 2048);
#pragma unroll
  for (int u = 0; u < 4; ++u) vr[u] = *(const bf16x8*)(vg + u * 8);
#pragma unroll
  for (int g = 0; g < 8; ++g) mr[g] = *(const f32x4*)(mp + g * 8);
#pragma unroll
  for (int u = 0; u < 4; ++u) *(bf16x8*)&Ks[0][u * 2048 + ksw] = kr[u];
#pragma unroll
  for (int u = 0; u < 4; ++u) *(bf16x8*)&Vts[0][vsw[u]] = vr[u];
  unsigned mbits;
  {
    float lo = 0.f, hi = 0.f;
#pragma unroll
    for (int g = 0; g < 4; ++g)
#pragma unroll
      for (int e = 0; e < 4; ++e) {
        lo = fmaf(mr[g][e],     (float)(1u << (g * 4 + e)), lo);
        hi = fmaf(mr[g + 4][e], (float)(1u << (g * 4 + e)), hi);
      }
    mbits = (unsigned)lo | ((unsigned)hi << 16);
  }
  __syncthreads();

  int cur = 0;
  for (int jt = 0; jt < 32; ++jt) {
    const int jn = (jt < 31) ? jt + 1 : 31;   // redundant reload on last iter
    // ---- issue prefetch for tile jn (in flight across the whole compute)
    {
      const __bf16* kgn = kg + (long)jn * 8192;
#pragma unroll
      for (int u = 0; u < 4; ++u) kr[u] = *(const bf16x8*)(kgn + u * 2048);
      const __bf16* vgn = vg + jn * 64;
#pragma unroll
      for (int u = 0; u < 4; ++u) vr[u] = *(const bf16x8*)(vgn + u * 8);
      const float* mpn = mp + jn * 64;
#pragma unroll
      for (int g = 0; g < 8; ++g) mr[g] = *(const f32x4*)(mpn + g * 8);
    }

    // ---- S^T = K Q^T : two 32x32 tiles (keys 0-31, 32-63) x 8 k-steps
    f32x16 c0, c1;
#pragma unroll
    for (int r = 0; r < 16; ++r) { c0[r] = 0.f; c1[r] = 0.f; }
#pragma unroll
    for (int kd = 0; kd < 8; ++kd) {
      const int col = (kd * 16 + H * 8) ^ swz;
      bf16x8 kf0 = *(const bf16x8*)&Ks[cur][l31 * 128 + col];
      bf16x8 kf1 = *(const bf16x8*)&Ks[cur][(32 + l31) * 128 + col];
      c0 = __builtin_amdgcn_mfma_f32_32x32x16_bf16(kf0, qf[kd], c0, 0, 0, 0);
      c1 = __builtin_amdgcn_mfma_f32_32x32x16_bf16(kf1, qf[kd], c1, 0, 0, 0);
    }

    // ---- masked online softmax; key for (c0,reg r) = bit r, (c1,r) = bit 16+r
    float tmx = -1e30f;
#pragma unroll
    for (int r = 0; r < 16; ++r) {
      float s0 = ((mbits >> r) & 1u) ? c0[r] : -1e30f;
      float s1 = ((mbits >> (16 + r)) & 1u) ? c1[r] : -1e30f;
      c0[r] = s0; c1[r] = s1;
      tmx = fmaxf(tmx, fmaxf(s0, s1));
    }
    tmx = fmaxf(tmx, __shfl_xor(tmx, 32));
    const bool grow = !__all(tmx <= mrow);
    const float mnew = fmaxf(mrow, tmx);
    const float alpha = exp2f(mrow - mnew);
    float rs = 0.0f;
#pragma unroll
    for (int r = 0; r < 16; ++r) {
      float p0 = exp2f(c0[r] - mnew);
      float p1 = exp2f(c1[r] - mnew);
      c0[r] = p0; c1[r] = p1;
      rs += p0 + p1;
    }
    rs += __shfl_xor(rs, 32);
    lrow = lrow * alpha + rs;
    mrow = mnew;

    // ---- rescale O (alpha is per-lane q — no shuffles needed)
    if (grow) {
#pragma unroll
      for (int ht = 0; ht < 4; ++ht)
#pragma unroll
        for (int r = 0; r < 16; ++r) O[ht][r] *= alpha;
    }

    // ---- O^T += V^T P^T ; P^T built in registers per 16-key step
#pragma unroll
    for (int s = 0; s < 4; ++s) {
      // cx = tile holding keys 32*(s>>1); reg block base 8*(s&1)
      const int rb = 8 * (s & 1);
      unsigned pA0, pA1, pB0, pB1;
      if (s < 2) {
        pA0 = pack2bf(c0[rb + 0], c0[rb + 1]); pA1 = pack2bf(c0[rb + 2], c0[rb + 3]);
        pB0 = pack2bf(c0[rb + 4], c0[rb + 5]); pB1 = pack2bf(c0[rb + 6], c0[rb + 7]);
      } else {
        pA0 = pack2bf(c1[rb + 0], c1[rb + 1]); pA1 = pack2bf(c1[rb + 2], c1[rb + 3]);
        pB0 = pack2bf(c1[rb + 4], c1[rb + 5]); pB1 = pack2bf(c1[rb + 6], c1[rb + 7]);
      }
      // cross-half exchange: lo lanes need hi's pA, hi lanes need lo's pB
      unsigned snd0 = H ? pA0 : pB0;
      unsigned snd1 = H ? pA1 : pB1;
      unsigned rcv0 = __shfl_xor(snd0, 32);
      unsigned rcv1 = __shfl_xor(snd1, 32);
      union { unsigned u[4]; bf16x8 v; } pb;
      pb.u[0] = H ? rcv0 : pA0;
      pb.u[1] = H ? rcv1 : pA1;
      pb.u[2] = H ? pB0 : rcv0;
      pb.u[3] = H ? pB1 : rcv1;
      const int vcol = (s * 16 + H * 8) ^ swz;
#pragma unroll
      for (int ht = 0; ht < 4; ++ht) {
        bf16x8 vf = *(const bf16x8*)&Vts[cur][(ht * 32 + l31) * 64 + vcol];
        O[ht] = __builtin_amdgcn_mfma_f32_32x32x16_bf16(vf, pb.v, O[ht], 0, 0, 0);
      }
    }

    // ---- stage prefetched tile jn into inactive buffers; pack its mask
#pragma unroll
    for (int u = 0; u < 4; ++u) *(bf16x8*)&Ks[cur ^ 1][u * 2048 + ksw] = kr[u];
#pragma unroll
    for (int u = 0; u < 4; ++u) *(bf16x8*)&Vts[cur ^ 1][vsw[u]] = vr[u];
    {
      float lo = 0.f, hi = 0.f;
#pragma unroll
      for (int g = 0; g < 4; ++g)
#pragma unroll
        for (int e = 0; e < 4; ++e) {
          lo = fmaf(mr[g][e],     (float)(1u << (g * 4 + e)), lo);
          hi = fmaf(mr[g + 4][e], (float)(1u << (g * 4 + e)), hi);
        }
      mbits = (unsigned)lo | ((unsigned)hi << 16);
    }
    __syncthreads();   // tile jn staged & visible; everyone done reading jt
    cur ^= 1;
  }

  // ---- epilogue: out[q][h] = O^T[h][q] / l ; h = ht*32 + 8*r4 + 4H + j
  const float inv = 1.0f / lrow;
  float* op = out + ((long)b * NN + qrow) * HID;
#pragma unroll
  for (int ht = 0; ht < 4; ++ht)
#pragma unroll
    for (int r4 = 0; r4 < 4; ++r4) {
      f32x4 v;
#pragma unroll
      for (int j = 0; j < 4; ++j) v[j] = O[ht][r4 * 4 + j] * inv;
      *(f32x4*)(op + ht * 32 + r4 * 8 + H * 4) = v;
    }
}

// ---------------------------------------------------------------------------
extern "C" void kernel_launch(void* const* d_in, const int* in_sizes, int n_in,
                              void* d_out, int out_size, void* d_ws, size_t ws_size,
                              hipStream_t stream) {
  const float* x    = (const float*)d_in[0];
  const float* mask = (const float*)d_in[1];
  const float* Wv   = (const float*)d_in[2];
  const float* bv   = (const float*)d_in[3];
  const float* Wk   = (const float*)d_in[4];
  const float* bk   = (const float*)d_in[5];
  const float* Wq   = (const float*)d_in[6];
  const float* bq   = (const float*)d_in[7];
  float* out = (float*)d_out;

  __bf16* ws = (__bf16*)d_ws;
  __bf16* wt   = ws;                      // 3 * 128*128
  __bf16* qbf  = ws + 3 * DIN * HID;      // B*N*H
  __bf16* kbf  = qbf + (long)BB * NN * HID;
  __bf16* vtbf = kbf + (long)BB * NN * HID;

  wt_kernel<<<3, 256, 0, stream>>>(Wq, Wk, Wv, wt);
  proj_kernel<<<BB * NN / 64, 256, 0, stream>>>(x, wt, bq, bk, bv, qbf, kbf, vtbf);
  attn_kernel<<<512, 256, 0, stream>>>(qbf, kbf, vtbf, mask, out);
}

// Round 4
// 842.159 us; speedup vs baseline: 1.0942x; 1.0382x over previous
//
#include <hip/hip_runtime.h>

#define DIN 128
#define HID 128
#define BB  32
#define NN  2048
#define LOG2E 1.44269504088896340736f

typedef float  f32x4   __attribute__((ext_vector_type(4)));
typedef __bf16 bf16x4v __attribute__((ext_vector_type(4)));
typedef __bf16 bf16x8  __attribute__((ext_vector_type(8)));

__device__ __forceinline__ float tanh_fast(float x) {
  // tanh(x) = 1 - 2/(e^{2x}+1); NaN-free for +-inf of exp
  float e = __expf(2.0f * x);
  return 1.0f - 2.0f / (e + 1.0f);
}

// ---------------------------------------------------------------------------
// Kernel 0: W[d][h] (fp32) -> wt[h][d] (bf16), for q,k,v. 3 blocks x 256.
// ---------------------------------------------------------------------------
__global__ __launch_bounds__(256) void wt_kernel(
    const float* __restrict__ Wq, const float* __restrict__ Wk,
    const float* __restrict__ Wv, __bf16* __restrict__ wt) {
  const float* W = (blockIdx.x == 0) ? Wq : (blockIdx.x == 1) ? Wk : Wv;
  __bf16* dst = wt + blockIdx.x * (DIN * HID);
  int t = threadIdx.x;
#pragma unroll
  for (int c = 0; c < 16; ++c) {
    int o = c * 1024 + t * 4;
    int d = o >> 7, h = o & 127;
    f32x4 v = *(const f32x4*)(W + d * HID + h);
    dst[(h + 0) * DIN + d] = (__bf16)v.x;
    dst[(h + 1) * DIN + d] = (__bf16)v.y;
    dst[(h + 2) * DIN + d] = (__bf16)v.z;
    dst[(h + 3) * DIN + d] = (__bf16)v.w;
  }
}

// ---------------------------------------------------------------------------
// Kernel A: q = tanh(xWq+bq)*LOG2E, k = tanh(xWk+bk) row-major bf16 [B*N][H];
//           vt = tanh(xWv+bv)^T per batch, bf16 [B][H][N].
// grid = B*N/64 blocks of 256 threads (4 waves; wave w owns rows 16w..16w+15).
// ---------------------------------------------------------------------------
__global__ __launch_bounds__(256) void proj_kernel(
    const float* __restrict__ x, const __bf16* __restrict__ wt,
    const float* __restrict__ bq, const float* __restrict__ bk,
    const float* __restrict__ bv, __bf16* __restrict__ qbf,
    __bf16* __restrict__ kbf, __bf16* __restrict__ vtbf) {
  int tid = threadIdx.x;
  int lane = tid & 63, w = tid >> 6;
  int l15 = lane & 15, quad = lane >> 4;
  long i0 = (long)blockIdx.x * 64;

  // x fragments: bx[nt][ks]: lane holds x[i0+nt*16+l15][ks*32+quad*8 .. +7]
  bf16x8 bx[4][4];
#pragma unroll
  for (int nt = 0; nt < 4; ++nt) {
    const float* xp = x + (i0 + nt * 16 + l15) * DIN;
#pragma unroll
    for (int ks = 0; ks < 4; ++ks) {
      int d0 = ks * 32 + quad * 8;
      f32x4 a = *(const f32x4*)(xp + d0);
      f32x4 b = *(const f32x4*)(xp + d0 + 4);
      bf16x8 f;
      f[0] = (__bf16)a.x; f[1] = (__bf16)a.y; f[2] = (__bf16)a.z; f[3] = (__bf16)a.w;
      f[4] = (__bf16)b.x; f[5] = (__bf16)b.y; f[6] = (__bf16)b.z; f[7] = (__bf16)b.w;
      bx[nt][ks] = f;
    }
  }

  // q and k: D[i][h] = sum_d x[i][d] * W[d][h]; A = x frag, B = wt[h][d]
#pragma unroll
  for (int p = 0; p < 2; ++p) {
    const __bf16* wtp = wt + p * DIN * HID;       // 0=q, 1=k
    const float* bias = (p == 0) ? bq : bk;
    __bf16* outp = (p == 0) ? qbf : kbf;
#pragma unroll
    for (int nt = 0; nt < 8; ++nt) {
      int h0 = nt * 16 + l15;
      f32x4 acc = {0.f, 0.f, 0.f, 0.f};
#pragma unroll
      for (int ks = 0; ks < 4; ++ks) {
        bf16x8 wf = *(const bf16x8*)(wtp + (long)h0 * DIN + ks * 32 + quad * 8);
        acc = __builtin_amdgcn_mfma_f32_16x16x32_bf16(bx[w][ks], wf, acc, 0, 0, 0);
      }
      float bcol = bias[h0];
      long rowb = i0 + w * 16 + quad * 4;
#pragma unroll
      for (int r = 0; r < 4; ++r) {
        float val = tanh_fast(acc[r] + bcol);
        if (p == 0) val *= LOG2E;   // fold log2(e) into q for exp2 softmax
        outp[(rowb + r) * HID + h0] = (__bf16)val;
      }
    }
  }

  // vt: D[h][n] = sum_d W[d][h] * x[n][d]; A = wt frag, B = x frag
  {
    const __bf16* wtp = wt + 2 * DIN * HID;
    long bb = i0 >> 11;            // batch index
    int nloc = (int)(i0 & 2047);   // row within batch
    long vbase = bb * (long)HID * NN;
#pragma unroll
    for (int s = 0; s < 2; ++s) {
      int hb = w * 32 + s * 16;
      bf16x8 af[4];
#pragma unroll
      for (int ks = 0; ks < 4; ++ks)
        af[ks] = *(const bf16x8*)(wtp + (long)(hb + l15) * DIN + ks * 32 + quad * 8);
      float bvr[4];
#pragma unroll
      for (int r = 0; r < 4; ++r) bvr[r] = bv[hb + quad * 4 + r];
#pragma unroll
      for (int nt = 0; nt < 4; ++nt) {
        f32x4 acc = {0.f, 0.f, 0.f, 0.f};
#pragma unroll
        for (int ks = 0; ks < 4; ++ks)
          acc = __builtin_amdgcn_mfma_f32_16x16x32_bf16(af[ks], bx[nt][ks], acc, 0, 0, 0);
        int hrow = hb + quad * 4;
        int ncol = nloc + nt * 16 + l15;
#pragma unroll
        for (int r = 0; r < 4; ++r) {
          float val = tanh_fast(acc[r] + bvr[r]);
          vtbf[vbase + (long)(hrow + r) * NN + ncol] = (__bf16)val;
        }
      }
    }
  }
}

// ---------------------------------------------------------------------------
// Kernel B: flash attention, software-pipelined (baseline-exact structure).
// grid = 512 blocks x 512 threads (8 waves). Block owns 128 q-rows.
// Wave w owns q rows i0+16w..+15 (i = lane&15 in the transposed-S layout).
// K-loop: 32 tiles of 64 keys; K/V/mask for tile j+1 register-prefetched
// during compute of tile j, staged to (single-buffered) LDS after barrier.
// Round-4 additions (strictly local): grow-skip of the exact-noop O-rescale
// (saves 32 VALU + 4 ds_bpermute per tile per wave in the common case) and
// s_setprio(1) around both MFMA clusters (T5).
// ---------------------------------------------------------------------------
#define KSTR 136   // Ks row stride: 272 B, 16B-aligned
#define VSTR 72    // Vts row stride: 144 B, 16B-aligned
#define PSTR 72    // P row stride: 144 B, 16B-aligned

__global__ __launch_bounds__(512, 4) void attn_kernel(
    const __bf16* __restrict__ qbf, const __bf16* __restrict__ kbf,
    const __bf16* __restrict__ vtbf, const float* __restrict__ mask,
    float* __restrict__ out) {
  __shared__ __bf16 Ks[64 * KSTR];       // 17408 B
  __shared__ __bf16 Vts[128 * VSTR];     // 18432 B
  __shared__ __bf16 Pl[8 * 16 * PSTR];   // 18432 B  (total 54272 B)

  const int tid = threadIdx.x;
  const int lane = tid & 63, w = tid >> 6;
  const int l15 = lane & 15, quad = lane >> 4;
  // XCD swizzle: 64 consecutive virtual blocks (= 4 whole batches) per XCD
  const int bid = blockIdx.x;
  const int vb = (bid >> 3) | ((bid & 7) << 6);
  const int b = vb >> 4;
  const int i0 = (vb & 15) * 128;
  const long kvbase = (long)b * NN * HID;

  // Q fragment (B operand of S^T): lane l15 = q-row, quad*8+e = k-dim
  bf16x8 qf[4];
  {
    const __bf16* qp = qbf + kvbase + (long)(i0 + w * 16 + l15) * HID + quad * 8;
#pragma unroll
    for (int ks = 0; ks < 4; ++ks) qf[ks] = *(const bf16x8*)(qp + ks * 32);
  }

  // staging geometry (512 threads, 2 passes per tile for each of K and Vt)
  const int krow = tid >> 4, kcol = (tid & 15) * 8;
  const int vrow = tid >> 3, vcol = (tid & 7) * 8;
  const __bf16* kg = kbf + kvbase + (long)krow * HID + kcol;
  const __bf16* vg = vtbf + (long)b * HID * NN + (long)vrow * NN + vcol;
  __bf16* ksd0 = Ks + krow * KSTR + kcol;
  __bf16* ksd1 = Ks + (krow + 32) * KSTR + kcol;
  __bf16* vsd0 = Vts + vrow * VSTR + vcol;
  __bf16* vsd1 = Vts + (vrow + 64) * VSTR + vcol;
  // mask: lane reads row i = i0+w*16+l15, 4 consecutive cols at quad*4
  const float* mp = mask + ((long)b * NN + (i0 + w * 16 + l15)) * NN + quad * 4;
  __bf16* Pw = Pl + w * 16 * PSTR;

  f32x4 O[8];
#pragma unroll
  for (int i = 0; i < 8; ++i) O[i] = (f32x4){0.f, 0.f, 0.f, 0.f};
  float mrow = -1e30f, lrow = 0.0f;   // per q-row i = l15 (replicated over quads)

  // ---- prologue: load + stage tile 0
  bf16x8 kr0 = *(const bf16x8*)(kg);
  bf16x8 kr1 = *(const bf16x8*)(kg + 32 * HID);
  bf16x8 vr0 = *(const bf16x8*)(vg);
  bf16x8 vr1 = *(const bf16x8*)(vg + (long)64 * NN);
  f32x4 mr[4];
#pragma unroll
  for (int t = 0; t < 4; ++t) mr[t] = *(const f32x4*)(mp + t * 16);
  *(bf16x8*)ksd0 = kr0; *(bf16x8*)ksd1 = kr1;
  *(bf16x8*)vsd0 = vr0; *(bf16x8*)vsd1 = vr1;
  unsigned mbits;
  {
    float mb = 0.f;
#pragma unroll
    for (int t = 0; t < 4; ++t)
#pragma unroll
      for (int r = 0; r < 4; ++r)
        mb = fmaf(mr[t][r], (float)(1u << (t * 4 + r)), mb);  // mask is exactly 0/1
    mbits = (unsigned)mb;
  }
  __syncthreads();

  for (int jt = 0; jt < 32; ++jt) {
    const int jn = (jt < 31) ? jt + 1 : 31;   // redundant reload on last iter
    // ---- issue prefetch for tile jn (in flight across the whole compute phase)
    {
      const __bf16* kgn = kg + (long)jn * 64 * HID;
      kr0 = *(const bf16x8*)(kgn);
      kr1 = *(const bf16x8*)(kgn + 32 * HID);
      const __bf16* vgn = vg + jn * 64;
      vr0 = *(const bf16x8*)(vgn);
      vr1 = *(const bf16x8*)(vgn + (long)64 * NN);
#pragma unroll
      for (int t = 0; t < 4; ++t) mr[t] = *(const f32x4*)(mp + jn * 64 + t * 16);
    }

    // ---- S^T = K Q^T : rows = keys (quad*4+r within subtile t), cols = q (l15)
    f32x4 pt[4];
    __builtin_amdgcn_s_setprio(1);
#pragma unroll
    for (int t = 0; t < 4; ++t) {
      f32x4 acc = {0.f, 0.f, 0.f, 0.f};
      const __bf16* kp = Ks + (t * 16 + l15) * KSTR + quad * 8;
#pragma unroll
      for (int ks = 0; ks < 4; ++ks) {
        bf16x8 kf = *(const bf16x8*)(kp + ks * 32);
        acc = __builtin_amdgcn_mfma_f32_16x16x32_bf16(kf, qf[ks], acc, 0, 0, 0);
      }
      pt[t] = acc;
    }
    __builtin_amdgcn_s_setprio(0);

    // ---- masked online softmax (log2 domain; q pre-scaled by log2 e)
    float tmx = -1e30f;
#pragma unroll
    for (int t = 0; t < 4; ++t)
#pragma unroll
      for (int r = 0; r < 4; ++r) {
        float s = ((mbits >> (t * 4 + r)) & 1u) ? pt[t][r] : -1e30f;
        pt[t][r] = s;
        tmx = fmaxf(tmx, s);
      }
    tmx = fmaxf(tmx, __shfl_xor(tmx, 16));
    tmx = fmaxf(tmx, __shfl_xor(tmx, 32));
    const bool grow = !__all(tmx <= mrow);   // any row max increased this tile?
    const float mnew = fmaxf(mrow, tmx);
    const float alpha = exp2f(mrow - mnew);  // == 1.0 exactly when !grow
    float rs = 0.0f;
#pragma unroll
    for (int t = 0; t < 4; ++t)
#pragma unroll
      for (int r = 0; r < 4; ++r) {
        float p = exp2f(pt[t][r] - mnew);
        pt[t][r] = p;
        rs += p;
      }
    rs += __shfl_xor(rs, 16);
    rs += __shfl_xor(rs, 32);
    lrow = lrow * alpha + rs;
    mrow = mnew;

    // ---- rescale O (O rows are i = quad*4+r; alpha lives at lane l15 = i).
    // grow==false -> alpha==1.0 for every row in the wave -> exact no-op:
    // skip 4 ds_bpermute broadcasts + 32 VALU (common case on random mask).
    if (grow) {
      float ar[4];
#pragma unroll
      for (int r = 0; r < 4; ++r) ar[r] = __shfl(alpha, (quad << 2) + r);
#pragma unroll
      for (int nt = 0; nt < 8; ++nt)
#pragma unroll
        for (int r = 0; r < 4; ++r) O[nt][r] *= ar[r];
    }

    // ---- P: S^T layout -> LDS [i][j] -> A-layout (wave-private, b64 writes)
#pragma unroll
    for (int t = 0; t < 4; ++t) {
      bf16x4v pb;
#pragma unroll
      for (int r = 0; r < 4; ++r) pb[r] = (__bf16)pt[t][r];
      *(bf16x4v*)(Pw + l15 * PSTR + t * 16 + quad * 4) = pb;
    }
    const bf16x8 pf0 = *(const bf16x8*)(Pw + l15 * PSTR + quad * 8);
    const bf16x8 pf1 = *(const bf16x8*)(Pw + l15 * PSTR + 32 + quad * 8);

    // ---- O += P V
    __builtin_amdgcn_s_setprio(1);
#pragma unroll
    for (int nt = 0; nt < 8; ++nt) {
      const __bf16* vp = Vts + (nt * 16 + l15) * VSTR + quad * 8;
      bf16x8 vf0 = *(const bf16x8*)(vp);
      bf16x8 vf1 = *(const bf16x8*)(vp + 32);
      O[nt] = __builtin_amdgcn_mfma_f32_16x16x32_bf16(pf0, vf0, O[nt], 0, 0, 0);
      O[nt] = __builtin_amdgcn_mfma_f32_16x16x32_bf16(pf1, vf1, O[nt], 0, 0, 0);
    }
    __builtin_amdgcn_s_setprio(0);

    __syncthreads();   // all waves done reading tile jt from LDS
    // ---- stage prefetched tile jn into LDS; compress its mask
    *(bf16x8*)ksd0 = kr0; *(bf16x8*)ksd1 = kr1;
    *(bf16x8*)vsd0 = vr0; *(bf16x8*)vsd1 = vr1;
    {
      float mb = 0.f;
#pragma unroll
      for (int t = 0; t < 4; ++t)
#pragma unroll
        for (int r = 0; r < 4; ++r)
          mb = fmaf(mr[t][r], (float)(1u << (t * 4 + r)), mb);
      mbits = (unsigned)mb;
    }
    __syncthreads();   // tile jn visible to all waves
  }

  // ---- epilogue: out[i][h] = O / l
  const float inv = 1.0f / lrow;
  float il[4];
#pragma unroll
  for (int r = 0; r < 4; ++r) il[r] = __shfl(inv, (quad << 2) + r);
  const long rowb = (long)b * NN + i0 + w * 16 + quad * 4;
#pragma unroll
  for (int r = 0; r < 4; ++r) {
    float* op = out + (rowb + r) * HID;
#pragma unroll
    for (int nt = 0; nt < 8; ++nt) op[nt * 16 + l15] = O[nt][r] * il[r];
  }
}

// ---------------------------------------------------------------------------
extern "C" void kernel_launch(void* const* d_in, const int* in_sizes, int n_in,
                              void* d_out, int out_size, void* d_ws, size_t ws_size,
                              hipStream_t stream) {
  const float* x    = (const float*)d_in[0];
  const float* mask = (const float*)d_in[1];
  const float* Wv   = (const float*)d_in[2];
  const float* bv   = (const float*)d_in[3];
  const float* Wk   = (const float*)d_in[4];
  const float* bk   = (const float*)d_in[5];
  const float* Wq   = (const float*)d_in[6];
  const float* bq   = (const float*)d_in[7];
  float* out = (float*)d_out;

  __bf16* ws = (__bf16*)d_ws;
  __bf16* wt   = ws;                      // 3 * 128*128
  __bf16* qbf  = ws + 3 * DIN * HID;      // B*N*H
  __bf16* kbf  = qbf + (long)BB * NN * HID;
  __bf16* vtbf = kbf + (long)BB * NN * HID;

  wt_kernel<<<3, 256, 0, stream>>>(Wq, Wk, Wv, wt);
  proj_kernel<<<BB * NN / 64, 256, 0, stream>>>(x, wt, bq, bk, bv, qbf, kbf, vtbf);
  attn_kernel<<<512, 512, 0, stream>>>(qbf, kbf, vtbf, mask, out);
}